// Round 1
// baseline (530.669 us; speedup 1.0000x reference)
//
#include <hip/hip_runtime.h>
#include <cmath>
#include <cstdint>

#define NTOK   16384
#define DM     512
#define NEXP   8
#define LOG100 4.605170185988092f

typedef _Float16 half8  __attribute__((ext_vector_type(8)));
typedef float    floatx4 __attribute__((ext_vector_type(4)));

#define MFMA_F16(a, b, c) __builtin_amdgcn_mfma_f32_16x16x32_f16((a), (b), (c), 0, 0, 0)

// async global->LDS, 16B per lane. LDS dest wave-uniform base (HW adds lane*16);
// global source address is per-lane.
__device__ __forceinline__ void gl_lds16(const void* g, void* l) {
    __builtin_amdgcn_global_load_lds(
        (const __attribute__((address_space(1))) void*)g,
        (__attribute__((address_space(3))) void*)l, 16, 0, 0);
}

// ---------------- ws layout ----------------
// ctrl floats @ws: [0..31] int cnt[2][2][8] | [32..47] imp[2][8] | [48..49] vq[2]
//                  [50..51] tsc[2] | [52..67] ia[2][8] | [128..8319] rmn[16*512]
// @ws+64KB:  float2 wts[2][16384]  (256KB)
// @ws+384KB: float2 bs[2][16384]   (256KB)
// @ws+704KB: uchar key[2][2][16384] (64KB)
// @ws+1MB:   w0pk 8MB | w1pk 4MB | h16 16MB | bkt(ushort) 2MB  => 31MB total
// xpk (32MB, interleaved hi/lo) lives in d_out's h1 region (dead until layer-1 GEMMs).

// =============================== prep ===============================
__global__ __launch_bounds__(256) void prep_kernel(
    const float* __restrict__ rm0, const float* __restrict__ rm1,
    const float* __restrict__ ca0, const float* __restrict__ ca1,
    const float* __restrict__ temp0, const float* __restrict__ temp1,
    float* __restrict__ ctrl, float* __restrict__ rmn)
{
    int tid = threadIdx.x, lane = tid & 63, w = tid >> 6;
    if (tid < 32) ((int*)ctrl)[tid] = 0;                       // cnt
    if (tid >= 32 && tid < 48) ctrl[tid] = 0.f;                // imp
    if (tid == 48 || tid == 49) ctrl[tid] = 0.f;               // vq
    if (tid == 50) ctrl[50] = expf(fminf(temp0[0], LOG100));
    if (tid == 51) ctrl[51] = expf(fminf(temp1[0], LOG100));
    if (tid >= 52 && tid < 68) {
        int i = tid - 52;
        ctrl[tid] = expf(fminf(i < 8 ? ca0[i] : ca1[i - 8], LOG100));
    }
    for (int r = w; r < 16; r += 4) {
        const float* src = (r < 8) ? (rm0 + r * DM) : (rm1 + (r - 8) * DM);
        float v[8]; float ss = 0.f;
        #pragma unroll
        for (int j = 0; j < 8; ++j) { v[j] = src[lane + 64 * j]; ss += v[j] * v[j]; }
        #pragma unroll
        for (int off = 32; off > 0; off >>= 1) ss += __shfl_xor(ss, off);
        float inv = 1.f / fmaxf(sqrtf(ss), 1e-12f);
        float* dst = rmn + r * DM;
        #pragma unroll
        for (int j = 0; j < 8; ++j) dst[lane + 64 * j] = v[j] * inv;
    }
}

// =============================== W tile pre-pack ===============================
// Packs W into the EXACT swizzled LDS image the GEMM stages, so every
// global_load_lds is a contiguous 1KB copy.
// w0pk: [e][nt(4)][kb(16)][j(16)][lane(64)][8 halves]; lane=(s,p): row=j*8+s,
//       chunk c=p^s: c<4 -> fp16-hi of W0[e][n][kb*32+c*8 ..+7], c>=4 -> fp16-lo.
// w1pk: [e][nt(4)][kb(8)][j(16)][lane][8]: chunk c=p^s -> W1[e][n][kb*64+c*8 ..].
__global__ __launch_bounds__(256) void pack_w_kernel(
    const float* __restrict__ W0, const float* __restrict__ W1,
    half8* __restrict__ w0pk, half8* __restrict__ w1pk)
{
    int i = blockIdx.x * 256 + threadIdx.x;      // 3072*256 = 768K = 512K(W0)+256K(W1)
    if (i < 512 * 1024) {
        int l = i & 63, j = (i >> 6) & 15, kb = (i >> 10) & 15, nt = (i >> 14) & 3, e = i >> 16;
        int s = l >> 3, p = l & 7, c = p ^ s;
        int n = nt * 128 + j * 8 + s;
        int k = kb * 32 + (c & 3) * 8;
        const float* src = W0 + ((size_t)e * DM + n) * DM + k;
        half8 v;
        #pragma unroll
        for (int t = 0; t < 8; ++t) {
            float f = src[t];
            _Float16 h = (_Float16)f;
            v[t] = (c < 4) ? h : (_Float16)(f - (float)h);
        }
        w0pk[i] = v;
    } else {
        int m = i - 512 * 1024;
        int l = m & 63, j = (m >> 6) & 15, kb = (m >> 10) & 7, nt = (m >> 13) & 3, e = m >> 15;
        int s = l >> 3, p = l & 7, c = p ^ s;
        int n = nt * 128 + j * 8 + s;
        int k = kb * 64 + c * 8;
        const float* src = W1 + ((size_t)e * DM + n) * DM + k;
        half8 v;
        #pragma unroll
        for (int t = 0; t < 8; ++t) v[t] = (_Float16)src[t];
        w1pk[m] = v;
    }
}

// =============================== routing (1 token / wave) ===============================
// split=1: writes interleaved hi/lo activation rows: xpk[tok][kb(16)][32 hi | 32 lo]
//          => each (tok,kb) is one contiguous 128B run for the GEMM's A staging.
// split=0: plain fp16 row [tok][512] (layer-1; already 128B-contiguous per (tok,kb)).
__global__ __launch_bounds__(256) void route_kernel(
    const float* __restrict__ src,      // [16384][512]
    const float* __restrict__ rmn,      // [8*512] normalized memory (this layer)
    int relu_in, int split,
    _Float16* __restrict__ dst,
    unsigned char* __restrict__ key,    // [2][16384] this layer (slot-major)
    float2* __restrict__ wts,           // [16384]
    float2* __restrict__ bs)            // [16384] (best,second)
{
    __shared__ float rmLds[NEXP * DM];
    int tid = threadIdx.x;
    for (int i = tid; i < NEXP * DM; i += 256) rmLds[i] = rmn[i];
    __syncthreads();
    int lane = tid & 63, w = tid >> 6;
    int token = blockIdx.x * 4 + w;

    const float* row = src + (size_t)token * DM;
    float x[8]; float ss = 0.f;
    #pragma unroll
    for (int j = 0; j < 8; ++j) {
        float v = row[lane + 64 * j];
        if (relu_in) v = fmaxf(v, 0.f);
        x[j] = v; ss += v * v;
    }
    if (split) {
        #pragma unroll
        for (int j = 0; j < 8; ++j) {
            int k = lane + 64 * j;
            size_t base = (size_t)token * 1024 + (size_t)((k >> 5) << 6) + (k & 31);
            _Float16 h = (_Float16)x[j];
            dst[base] = h;
            dst[base + 32] = (_Float16)(x[j] - (float)h);
        }
    } else {
        #pragma unroll
        for (int j = 0; j < 8; ++j)
            dst[(size_t)token * DM + lane + 64 * j] = (_Float16)x[j];
    }
    float d[8];
    #pragma unroll
    for (int e = 0; e < 8; ++e) {
        float a = 0.f;
        #pragma unroll
        for (int j = 0; j < 8; ++j) a += x[j] * rmLds[e * DM + lane + 64 * j];
        d[e] = a;
    }
    #pragma unroll
    for (int off = 32; off > 0; off >>= 1) {
        ss += __shfl_xor(ss, off);
        #pragma unroll
        for (int e = 0; e < 8; ++e) d[e] += __shfl_xor(d[e], off);
    }
    float inv = 1.f / fmaxf(sqrtf(ss), 1e-12f);
    float best = -1e30f, second = -1e30f; int be = 0, se = 0;
    #pragma unroll
    for (int e = 0; e < 8; ++e) {
        float de = d[e] * inv;
        if (de > best)        { second = best; se = be; best = de; be = e; }
        else if (de > second) { second = de; se = e; }
    }
    float z = expf(second - best);
    float w0 = 1.f / (1.f + z), w1 = z / (1.f + z);
    if (lane == 0) {
        key[token] = (unsigned char)be;
        key[NTOK + token] = (unsigned char)se;
        wts[token] = make_float2(w0, w1);
        bs[token] = make_float2(best, second);
    }
}

// =============================== bucket compaction ===============================
__global__ __launch_bounds__(256) void compact_kernel(
    const unsigned char* __restrict__ key,  // [2][16384] this layer
    const float2* __restrict__ wts,         // [16384]
    const float2* __restrict__ bs,          // [16384]
    int* __restrict__ cnt,                  // [2][8] this layer
    unsigned short* __restrict__ bkt,       // [2][8][16384] this layer
    float* __restrict__ imp,                // [8] this layer
    float* __restrict__ vq_acc)             // &vq[layer]
{
    int slot = blockIdx.x >> 3, e = blockIdx.x & 7;
    const unsigned char* k = key + slot * NTOK;
    unsigned short* ob = bkt + (size_t)(slot * 8 + e) * NTOK;
    __shared__ int wc[2][4];
    int tid = threadIdx.x, lane = tid & 63, w = tid >> 6;
    int base = 0;
    float wsum = 0.f, vqs = 0.f;
    for (int c = 0; c < 64; ++c) {
        int tok = c * 256 + tid;
        bool m = (k[tok] == (unsigned char)e);
        unsigned long long mask = __ballot(m);
        int p = c & 1;
        if (lane == 0) wc[p][w] = __popcll(mask);
        __syncthreads();
        int off = base;
        for (int i = 0; i < w; ++i) off += wc[p][i];
        if (m) {
            int pre = __popcll(mask & ((1ull << lane) - 1ull));
            ob[off + pre] = (unsigned short)tok;
            float2 wp = wts[tok]; float2 b2 = bs[tok];
            float wv = slot ? wp.y : wp.x;
            wsum += wv;
            vqs  += wv * (slot ? b2.y : b2.x);
        }
        base += wc[p][0] + wc[p][1] + wc[p][2] + wc[p][3];
    }
    #pragma unroll
    for (int off = 32; off > 0; off >>= 1) {
        wsum += __shfl_xor(wsum, off);
        vqs  += __shfl_xor(vqs, off);
    }
    __shared__ float rw[4], rv[4];
    if (lane == 0) { rw[w] = wsum; rv[w] = vqs; }
    __syncthreads();
    if (tid == 0) {
        cnt[slot * 8 + e] = base;
        float W = rw[0] + rw[1] + rw[2] + rw[3];
        float V = rv[0] + rv[1] + rv[2] + rv[3];
        atomicAdd(&imp[e], W);
        atomicAdd(vq_acc, -V);
    }
}

// =============================== grouped GEMM ===============================
// 128x128 tile, 4 waves (2x2 of 64x64), 16x16x32 f16 MFMA.
// 2-phase double-buffered pipeline (T3-minimum): stage tile kb+1 || compute tile kb,
// one barrier per K-step. LDS: 2 x (16KB A + 16KB B) = 64KB -> 2 blocks/CU.
// B staged from pre-packed tile images (contiguous 1KB per global_load_lds).
// A staged from interleaved rows: one 128B contiguous run per (tok,kb).
// SPLIT: KSTEP=32, chunks 0-3=hi 4-7=lo, 3 MFMA passes. Plain: KSTEP=64.
template <bool SPLIT>
__global__ __launch_bounds__(256) void gemm_kernel(
    const _Float16* __restrict__ A,      // SPLIT: xpk [tok][1024] ; else h16 [tok][512]
    const _Float16* __restrict__ Wpk,    // packed tiles
    const float* __restrict__ bias,      // [8][512]
    const float* __restrict__ iav,       // [8]
    const float* __restrict__ tscp,
    const int* __restrict__ cnt,         // [8] this layer+slot
    const unsigned short* __restrict__ bkt, // [8][16384]
    const float2* __restrict__ wts,      // [16384]
    int slot, int accum,
    float* __restrict__ outp)
{
    __shared__ __align__(16) _Float16 lds[2 * 16384];
    __shared__ int tokLds[128];

    // bijective XCD swizzle (1024 % 8 == 0): XCD k owns expert k's tiles
    // -> expert's W tile image + token stream stay in one XCD's L2.
    int bx = ((blockIdx.x & 7) << 7) | (blockIdx.x >> 3);
    int e = bx >> 7, mt = bx & 127;
    int M = cnt[e];
    int m0 = mt << 7;
    if (m0 >= M) return;
    int nt = blockIdx.y, n0 = nt << 7;
    int valid = min(128, M - m0);
    int tid = threadIdx.x, lane = tid & 63, w = tid >> 6;
    if (tid < 128) tokLds[tid] = bkt[e * NTOK + m0 + min(tid, valid - 1)];
    __syncthreads();

    int subRow = lane >> 3, p = lane & 7;
    int cSt = p ^ subRow;
    int wm = w >> 1, wn = w & 1;
    int r0 = wm * 64, c0 = wn * 64;
    int q = lane >> 4, l15 = lane & 15;

    constexpr int KIT = SPLIT ? 16 : 8;
    constexpr int AS  = SPLIT ? 1024 : 512;

    int tokR[4];
    #pragma unroll
    for (int jj = 0; jj < 4; ++jj) tokR[jj] = tokLds[(w + jj * 4) * 8 + subRow];

    const _Float16* wtile = Wpk + (size_t)(e * 4 + nt) * KIT * 8192;

    floatx4 acc[4][4];
    #pragma unroll
    for (int mi = 0; mi < 4; ++mi)
        #pragma unroll
        for (int ni = 0; ni < 4; ++ni) acc[mi][ni] = (floatx4){0.f, 0.f, 0.f, 0.f};

    auto stage = [&](int kb, int buf) {
        _Float16* dA = lds + buf * 16384;
        _Float16* dB = dA + 8192;
        #pragma unroll
        for (int jj = 0; jj < 4; ++jj) {   // A: 8 x 128B contiguous runs / instr
            int j = w + jj * 4;
            gl_lds16(A + (size_t)tokR[jj] * AS + kb * 64 + cSt * 8, (void*)(dA + j * 512));
        }
        const _Float16* wb = wtile + (size_t)kb * 8192;
        #pragma unroll
        for (int jj = 0; jj < 4; ++jj) {   // B: contiguous 1KB / instr
            int j = w + jj * 4;
            gl_lds16(wb + j * 512 + lane * 8, (void*)(dB + j * 512));
        }
    };

    auto compute = [&](int buf) {
        const _Float16* bA = lds + buf * 16384;
        const _Float16* bB = bA + 8192;
        if constexpr (SPLIT) {
            half8 ah[4], al[4];
            #pragma unroll
            for (int mi = 0; mi < 4; ++mi) {
                int r = r0 + mi * 16 + l15;
                int ph = q ^ (r & 7), pl = (q + 4) ^ (r & 7);
                ah[mi] = *(const half8*)(bA + r * 64 + ph * 8);
                al[mi] = *(const half8*)(bA + r * 64 + pl * 8);
            }
            #pragma unroll
            for (int ni = 0; ni < 4; ++ni) {
                int r = c0 + ni * 16 + l15;
                int ph = q ^ (r & 7), pl = (q + 4) ^ (r & 7);
                half8 bh = *(const half8*)(bB + r * 64 + ph * 8);
                half8 bl = *(const half8*)(bB + r * 64 + pl * 8);
                #pragma unroll
                for (int mi = 0; mi < 4; ++mi) acc[mi][ni] = MFMA_F16(ah[mi], bh, acc[mi][ni]);
                #pragma unroll
                for (int mi = 0; mi < 4; ++mi) acc[mi][ni] = MFMA_F16(ah[mi], bl, acc[mi][ni]);
                #pragma unroll
                for (int mi = 0; mi < 4; ++mi) acc[mi][ni] = MFMA_F16(al[mi], bh, acc[mi][ni]);
            }
        } else {
            #pragma unroll
            for (int ks = 0; ks < 2; ++ks) {
                half8 a[4];
                #pragma unroll
                for (int mi = 0; mi < 4; ++mi) {
                    int r = r0 + mi * 16 + l15;
                    int pc = (ks * 4 + q) ^ (r & 7);
                    a[mi] = *(const half8*)(bA + r * 64 + pc * 8);
                }
                #pragma unroll
                for (int ni = 0; ni < 4; ++ni) {
                    int r = c0 + ni * 16 + l15;
                    int pc = (ks * 4 + q) ^ (r & 7);
                    half8 b = *(const half8*)(bB + r * 64 + pc * 8);
                    #pragma unroll
                    for (int mi = 0; mi < 4; ++mi) acc[mi][ni] = MFMA_F16(a[mi], b, acc[mi][ni]);
                }
            }
        }
    };

    stage(0, 0);
    __syncthreads();
    int cur = 0;
    for (int kb = 0; kb < KIT - 1; ++kb) {
        stage(kb + 1, cur ^ 1);      // issue next tile's loads FIRST
        compute(cur);                // ds_read + MFMA current tile
        __syncthreads();             // single drain per K-step
        cur ^= 1;
    }
    compute(cur);

    // epilogue: C/D layout col=lane&15, row=(lane>>4)*4+reg
    float t = *tscp, iae = iav[e];
    float bv[4];
    #pragma unroll
    for (int ni = 0; ni < 4; ++ni) bv[ni] = bias[e * DM + n0 + c0 + ni * 16 + l15];
    #pragma unroll
    for (int mi = 0; mi < 4; ++mi) {
        int liBase = r0 + mi * 16 + q * 4;
        #pragma unroll
        for (int reg = 0; reg < 4; ++reg) {
            int li = liBase + reg;
            if (li < valid) {
                int tok = tokLds[li];
                float2 wp = wts[tok];
                float wgt = slot ? wp.y : wp.x;
                float sg = t * wgt * iae, sb = t * wgt;
                float* orow = outp + (size_t)tok * DM + n0;
                #pragma unroll
                for (int ni = 0; ni < 4; ++ni) {
                    float v = acc[mi][ni][reg] * sg + bv[ni] * sb;
                    int c = c0 + ni * 16 + l15;
                    if (accum) orow[c] += v; else orow[c] = v;
                }
            }
        }
    }
}

// =============================== finalize aux ===============================
__global__ void finalize_kernel(const float* __restrict__ ctrl, float* __restrict__ outp)
{
    if (threadIdx.x == 0) {
        float aux = 0.f;
        for (int l = 0; l < 2; ++l) {
            float vq = ctrl[48 + l] / (float)NTOK;
            float mean = 0.f;
            for (int e = 0; e < 8; ++e) mean += ctrl[32 + l * 8 + e];
            mean *= 0.125f;
            float s = 0.f;
            for (int e = 0; e < 8; ++e) {
                float d = ctrl[32 + l * 8 + e] - mean;
                s += d * d;
            }
            float var = s / 7.f;                       // ddof=1
            float lb = var / (mean * mean + 1e-10f);
            aux += 0.05f * vq + 0.01f * lb;
        }
        *outp = aux;
    }
}

// =============================== launch ===============================
extern "C" void kernel_launch(void* const* d_in, const int* in_sizes, int n_in,
                              void* d_out, int out_size, void* d_ws, size_t ws_size,
                              hipStream_t stream) {
    const float* x     = (const float*)d_in[0];
    const float* rm0   = (const float*)d_in[1];
    const float* W0    = (const float*)d_in[2];
    const float* b0    = (const float*)d_in[3];
    const float* temp0 = (const float*)d_in[4];
    const float* ca0   = (const float*)d_in[5];
    const float* rm1   = (const float*)d_in[6];
    const float* W1    = (const float*)d_in[7];
    const float* b1    = (const float*)d_in[8];
    const float* temp1 = (const float*)d_in[9];
    const float* ca1   = (const float*)d_in[10];
    float* out = (float*)d_out;

    char* ws = (char*)d_ws;
    float* ctrl = (float*)ws;
    int*   cnt  = (int*)ctrl;                 // [2][2][8]
    float* imp  = ctrl + 32;                  // [2][8]
    float* vq   = ctrl + 48;                  // [2]
    float* tsc  = ctrl + 50;                  // [2]
    float* ia   = ctrl + 52;                  // [2][8]
    float* rmn  = ctrl + 128;                 // [16][512]
    float2*        wts = (float2*)(ws + (size_t)64  * 1024);  // [2][16384]
    float2*        bs  = (float2*)(ws + (size_t)384 * 1024);  // [2][16384]
    unsigned char* key = (unsigned char*)(ws + (size_t)704 * 1024); // [2][2][16384]

    char* big = ws + (1 << 20);
    half8*          w0pk8 = (half8*)(big);                                 // 8MB
    half8*          w1pk8 = (half8*)(big + (size_t)8  * 1024 * 1024);      // 4MB
    const _Float16* w0pk  = (const _Float16*)w0pk8;
    const _Float16* w1pk  = (const _Float16*)w1pk8;
    _Float16*       h16   = (_Float16*)(big + (size_t)12 * 1024 * 1024);   // 16MB
    unsigned short* bkt   = (unsigned short*)(big + (size_t)28 * 1024 * 1024); // 2MB
    // total ws use: 31MB

    // xpk (interleaved hi/lo activations) lives in d_out's h1 region (32MB),
    // dead until layer-1 GEMMs write h1.
    _Float16* xpk = (_Float16*)(out + (size_t)NTOK * DM);

    prep_kernel<<<1, 256, 0, stream>>>(rm0, rm1, ca0, ca1, temp0, temp1, ctrl, rmn);
    pack_w_kernel<<<3072, 256, 0, stream>>>(W0, W1, w0pk8, w1pk8);

    // layer 0
    route_kernel<<<4096, 256, 0, stream>>>(x, rmn, 0, 1, xpk, key, wts, bs);
    compact_kernel<<<16, 256, 0, stream>>>(key, wts, bs, cnt, bkt, imp, vq);
    gemm_kernel<true><<<dim3(1024, 4), 256, 0, stream>>>(xpk, w0pk, b0, ia, tsc,
        cnt, bkt, wts, 0, 0, out);
    gemm_kernel<true><<<dim3(1024, 4), 256, 0, stream>>>(xpk, w0pk, b0, ia, tsc,
        cnt + 8, bkt + 8 * NTOK, wts, 1, 1, out);

    // layer 1 (routes on h_emb in d_out; relu + h->fp16 fused in route)
    route_kernel<<<4096, 256, 0, stream>>>(out, rmn + 4096, 1, 0, h16,
        key + 2 * NTOK, wts + NTOK, bs + NTOK);
    compact_kernel<<<16, 256, 0, stream>>>(key + 2 * NTOK, wts + NTOK, bs + NTOK,
        cnt + 16, bkt + 16 * NTOK, imp + 8, vq + 1);
    gemm_kernel<false><<<dim3(1024, 4), 256, 0, stream>>>(h16, w1pk, b1, ia + 8, tsc + 1,
        cnt + 16, bkt + 16 * NTOK, wts + NTOK, 0, 0, out + (size_t)NTOK * DM);
    gemm_kernel<false><<<dim3(1024, 4), 256, 0, stream>>>(h16, w1pk, b1, ia + 8, tsc + 1,
        cnt + 24, bkt + 24 * NTOK, wts + NTOK, 1, 1, out + (size_t)NTOK * DM);

    finalize_kernel<<<1, 64, 0, stream>>>(ctrl, out + (size_t)2 * NTOK * DM);
}

// Round 2
// 486.503 us; speedup vs baseline: 1.0908x; 1.0908x over previous
//
#include <hip/hip_runtime.h>
#include <cmath>
#include <cstdint>

#define NTOK   16384
#define NEXP   8
#define DM     512
#define LOG100 4.605170185988092f

typedef _Float16 half8  __attribute__((ext_vector_type(8)));
typedef float    floatx4 __attribute__((ext_vector_type(4)));

#define MFMA_F16(a, b, c) __builtin_amdgcn_mfma_f32_16x16x32_f16((a), (b), (c), 0, 0, 0)

// async global->LDS, 16B per lane. LDS dest wave-uniform base (HW adds lane*16);
// global source address is per-lane.
__device__ __forceinline__ void gl_lds16(const void* g, void* l) {
    __builtin_amdgcn_global_load_lds(
        (const __attribute__((address_space(1))) void*)g,
        (__attribute__((address_space(3))) void*)l, 16, 0, 0);
}

// ---------------- ws layout ----------------
// ctrl floats @ws: [0..31] int cnt[2][2][8] | [32..47] imp[2][8] | [48..49] vq[2]
//                  [50..51] tsc[2] | [52..67] ia[2][8] | [128..8319] rmn[16*512]
// @ws+64KB:  float2 wts[2][16384]  (256KB)
// @ws+384KB: float2 bs[2][16384]   (256KB)
// @ws+704KB: uchar key[2][2][16384] (64KB)
// @ws+1MB:   w0pk 8MB | w1pk 4MB | h16 16MB | bkt(ushort) 2MB  => 31MB total
// xpk (32MB, interleaved hi/lo) lives in d_out's h1 region (dead until layer-1 GEMMs).

// =============================== prep ===============================
__global__ __launch_bounds__(256) void prep_kernel(
    const float* __restrict__ rm0, const float* __restrict__ rm1,
    const float* __restrict__ ca0, const float* __restrict__ ca1,
    const float* __restrict__ temp0, const float* __restrict__ temp1,
    float* __restrict__ ctrl, float* __restrict__ rmn)
{
    int tid = threadIdx.x, lane = tid & 63, w = tid >> 6;
    if (tid < 32) ((int*)ctrl)[tid] = 0;                       // cnt
    if (tid >= 32 && tid < 48) ctrl[tid] = 0.f;                // imp
    if (tid == 48 || tid == 49) ctrl[tid] = 0.f;               // vq
    if (tid == 50) ctrl[50] = expf(fminf(temp0[0], LOG100));
    if (tid == 51) ctrl[51] = expf(fminf(temp1[0], LOG100));
    if (tid >= 52 && tid < 68) {
        int i = tid - 52;
        ctrl[tid] = expf(fminf(i < 8 ? ca0[i] : ca1[i - 8], LOG100));
    }
    for (int r = w; r < 16; r += 4) {
        const float* src = (r < 8) ? (rm0 + r * DM) : (rm1 + (r - 8) * DM);
        float v[8]; float ss = 0.f;
        #pragma unroll
        for (int j = 0; j < 8; ++j) { v[j] = src[lane + 64 * j]; ss += v[j] * v[j]; }
        #pragma unroll
        for (int off = 32; off > 0; off >>= 1) ss += __shfl_xor(ss, off);
        float inv = 1.f / fmaxf(sqrtf(ss), 1e-12f);
        float* dst = rmn + r * DM;
        #pragma unroll
        for (int j = 0; j < 8; ++j) dst[lane + 64 * j] = v[j] * inv;
    }
}

// =============================== W tile pre-pack ===============================
// Packs W into the EXACT swizzled LDS image the GEMM stages, so every
// global_load_lds is a contiguous 1KB copy.
// w0pk: [e][nt(4)][kb(16)][j(16)][lane(64)][8 halves]; lane=(s,p): row=j*8+s,
//       chunk c=p^s: c<4 -> fp16-hi of W0[e][n][kb*32+c*8 ..+7], c>=4 -> fp16-lo.
// w1pk: [e][nt(4)][kb(8)][j(16)][lane][8]: chunk c=p^s -> W1[e][n][kb*64+c*8 ..].
__global__ __launch_bounds__(256) void pack_w_kernel(
    const float* __restrict__ W0, const float* __restrict__ W1,
    half8* __restrict__ w0pk, half8* __restrict__ w1pk)
{
    int i = blockIdx.x * 256 + threadIdx.x;      // 3072*256 = 768K = 512K(W0)+256K(W1)
    if (i < 512 * 1024) {
        int l = i & 63, j = (i >> 6) & 15, kb = (i >> 10) & 15, nt = (i >> 14) & 3, e = i >> 16;
        int s = l >> 3, p = l & 7, c = p ^ s;
        int n = nt * 128 + j * 8 + s;
        int k = kb * 32 + (c & 3) * 8;
        const float* src = W0 + ((size_t)e * DM + n) * DM + k;
        half8 v;
        #pragma unroll
        for (int t = 0; t < 8; ++t) {
            float f = src[t];
            _Float16 h = (_Float16)f;
            v[t] = (c < 4) ? h : (_Float16)(f - (float)h);
        }
        w0pk[i] = v;
    } else {
        int m = i - 512 * 1024;
        int l = m & 63, j = (m >> 6) & 15, kb = (m >> 10) & 7, nt = (m >> 13) & 3, e = m >> 15;
        int s = l >> 3, p = l & 7, c = p ^ s;
        int n = nt * 128 + j * 8 + s;
        int k = kb * 64 + c * 8;
        const float* src = W1 + ((size_t)e * DM + n) * DM + k;
        half8 v;
        #pragma unroll
        for (int t = 0; t < 8; ++t) v[t] = (_Float16)src[t];
        w1pk[m] = v;
    }
}

// =============================== routing (1 token / wave) ===============================
// split=1: writes interleaved hi/lo activation rows: xpk[tok][kb(16)][32 hi | 32 lo]
//          => each (tok,kb) is one contiguous 128B run for the GEMM's A staging.
// split=0: plain fp16 row [tok][512] (layer-1; already 128B-contiguous per (tok,kb)).
__global__ __launch_bounds__(256) void route_kernel(
    const float* __restrict__ src,      // [16384][512]
    const float* __restrict__ rmn,      // [8*512] normalized memory (this layer)
    int relu_in, int split,
    _Float16* __restrict__ dst,
    unsigned char* __restrict__ key,    // [2][16384] this layer (slot-major)
    float2* __restrict__ wts,           // [16384]
    float2* __restrict__ bs)            // [16384] (best,second)
{
    __shared__ float rmLds[NEXP * DM];
    int tid = threadIdx.x;
    for (int i = tid; i < NEXP * DM; i += 256) rmLds[i] = rmn[i];
    __syncthreads();
    int lane = tid & 63, w = tid >> 6;
    int token = blockIdx.x * 4 + w;

    const float* row = src + (size_t)token * DM;
    float x[8]; float ss = 0.f;
    #pragma unroll
    for (int j = 0; j < 8; ++j) {
        float v = row[lane + 64 * j];
        if (relu_in) v = fmaxf(v, 0.f);
        x[j] = v; ss += v * v;
    }
    if (split) {
        #pragma unroll
        for (int j = 0; j < 8; ++j) {
            int k = lane + 64 * j;
            size_t base = (size_t)token * 1024 + (size_t)((k >> 5) << 6) + (k & 31);
            _Float16 h = (_Float16)x[j];
            dst[base] = h;
            dst[base + 32] = (_Float16)(x[j] - (float)h);
        }
    } else {
        #pragma unroll
        for (int j = 0; j < 8; ++j)
            dst[(size_t)token * DM + lane + 64 * j] = (_Float16)x[j];
    }
    float d[8];
    #pragma unroll
    for (int e = 0; e < 8; ++e) {
        float a = 0.f;
        #pragma unroll
        for (int j = 0; j < 8; ++j) a += x[j] * rmLds[e * DM + lane + 64 * j];
        d[e] = a;
    }
    #pragma unroll
    for (int off = 32; off > 0; off >>= 1) {
        ss += __shfl_xor(ss, off);
        #pragma unroll
        for (int e = 0; e < 8; ++e) d[e] += __shfl_xor(d[e], off);
    }
    float inv = 1.f / fmaxf(sqrtf(ss), 1e-12f);
    float best = -1e30f, second = -1e30f; int be = 0, se = 0;
    #pragma unroll
    for (int e = 0; e < 8; ++e) {
        float de = d[e] * inv;
        if (de > best)        { second = best; se = be; best = de; be = e; }
        else if (de > second) { second = de; se = e; }
    }
    float z = expf(second - best);
    float w0 = 1.f / (1.f + z), w1 = z / (1.f + z);
    if (lane == 0) {
        key[token] = (unsigned char)be;
        key[NTOK + token] = (unsigned char)se;
        wts[token] = make_float2(w0, w1);
        bs[token] = make_float2(best, second);
    }
}

// =============================== bucket compaction ===============================
// grid (16, 8): blockIdx.x = slot*8+e, blockIdx.y = 2048-token chunk.
// Wave-level compaction with atomic base allocation (no barriers in the scan).
// Bucket order is arbitrary -- numerically irrelevant (each token's output row
// is computed independently; tile membership doesn't change its value).
__global__ __launch_bounds__(256) void compact_kernel(
    const unsigned char* __restrict__ key,  // [2][16384] this layer
    const float2* __restrict__ wts,         // [16384]
    const float2* __restrict__ bs,          // [16384]
    int* __restrict__ cnt,                  // [2][8] this layer (pre-zeroed by prep)
    unsigned short* __restrict__ bkt,       // [2][8][16384] this layer
    float* __restrict__ imp,                // [8] this layer
    float* __restrict__ vq_acc)             // &vq[layer]
{
    int slot = blockIdx.x >> 3, e = blockIdx.x & 7;
    int chunk = blockIdx.y;
    const unsigned char* k = key + slot * NTOK;
    unsigned short* ob = bkt + (size_t)(slot * 8 + e) * NTOK;
    int tid = threadIdx.x, lane = tid & 63, w = tid >> 6;
    float wsum = 0.f, vqs = 0.f;
    for (int c = 0; c < 8; ++c) {
        int tok = chunk * 2048 + c * 256 + tid;
        bool m = (k[tok] == (unsigned char)e);
        unsigned long long mask = __ballot(m);
        int wcount = __popcll(mask);
        int wbase = 0;
        if (lane == 0 && wcount) wbase = atomicAdd(&cnt[slot * 8 + e], wcount);
        wbase = __shfl(wbase, 0);
        if (m) {
            int pre = __popcll(mask & ((1ull << lane) - 1ull));
            ob[wbase + pre] = (unsigned short)tok;
            float2 wp = wts[tok]; float2 b2 = bs[tok];
            float wv = slot ? wp.y : wp.x;
            wsum += wv;
            vqs  += wv * (slot ? b2.y : b2.x);
        }
    }
    #pragma unroll
    for (int off = 32; off > 0; off >>= 1) {
        wsum += __shfl_xor(wsum, off);
        vqs  += __shfl_xor(vqs, off);
    }
    __shared__ float rw[4], rv[4];
    if (lane == 0) { rw[w] = wsum; rv[w] = vqs; }
    __syncthreads();
    if (tid == 0) {
        atomicAdd(&imp[e], rw[0] + rw[1] + rw[2] + rw[3]);
        atomicAdd(vq_acc, -(rv[0] + rv[1] + rv[2] + rv[3]));
    }
}

// =============================== grouped GEMM ===============================
// COMPACT-TILE GRID: grid (135, 4). Each block decodes its (expert, m-tile) from
// a prefix sum over cnt[8] -- no early-exit churn, all useful blocks co-resident
// from t=0 (sum_e ceil(M_e/128) <= 135; LDS 66KB -> 2 blocks/CU -> capacity 512).
// 128x128 tile, 4 waves (2x2 of 64x64), 16x16x32 f16 MFMA.
// 2-phase double-buffered pipeline: stage tile kb+1 || compute tile kb, one
// barrier per K-step. B from pre-packed tile images (contiguous 1KB per
// global_load_lds); A rows contiguous 128B per (tok, K-step).
// SPLIT: KSTEP=32, chunks 0-3=hi 4-7=lo, 3 MFMA passes. Plain: KSTEP=64.
template <bool SPLIT>
__global__ __launch_bounds__(256) void gemm_kernel(
    const _Float16* __restrict__ A,      // SPLIT: xpk [tok][1024] ; else h16 [tok][512]
    const _Float16* __restrict__ Wpk,    // packed tiles
    const float* __restrict__ bias,      // [8][512]
    const float* __restrict__ iav,       // [8]
    const float* __restrict__ tscp,
    const int* __restrict__ cnt,         // [8] this layer+slot
    const unsigned short* __restrict__ bkt, // [8][16384]
    const float2* __restrict__ wts,      // [16384]
    int slot, int accum,
    float* __restrict__ outp)
{
    __shared__ __align__(16) _Float16 lds[2 * 16384];
    __shared__ int tokLds[128];

    // compact tile decode: tile t -> (e, m0) via prefix over ceil(cnt[e]/128)
    int t = blockIdx.x;
    int e = -1, m0 = 0, M = 0, acc = 0;
    #pragma unroll
    for (int ee = 0; ee < 8; ++ee) {
        int Me = cnt[ee];
        int ne = (Me + 127) >> 7;
        if (t >= acc && t < acc + ne) { e = ee; m0 = (t - acc) << 7; M = Me; }
        acc += ne;
    }
    if (e < 0) return;                   // beyond total tiles (<= 7*4 blocks)
    int nt = blockIdx.y, n0 = nt << 7;
    int valid = min(128, M - m0);
    int tid = threadIdx.x, lane = tid & 63, w = tid >> 6;
    if (tid < 128) tokLds[tid] = bkt[e * NTOK + m0 + min(tid, valid - 1)];
    __syncthreads();

    int subRow = lane >> 3, p = lane & 7;
    int cSt = p ^ subRow;
    int wm = w >> 1, wn = w & 1;
    int r0 = wm * 64, c0 = wn * 64;
    int q = lane >> 4, l15 = lane & 15;

    constexpr int KIT = SPLIT ? 16 : 8;
    constexpr int AS  = SPLIT ? 1024 : 512;

    int tokR[4];
    #pragma unroll
    for (int jj = 0; jj < 4; ++jj) tokR[jj] = tokLds[(w + jj * 4) * 8 + subRow];

    const _Float16* wtile = Wpk + (size_t)(e * 4 + nt) * KIT * 8192;

    floatx4 accu[4][4];
    #pragma unroll
    for (int mi = 0; mi < 4; ++mi)
        #pragma unroll
        for (int ni = 0; ni < 4; ++ni) accu[mi][ni] = (floatx4){0.f, 0.f, 0.f, 0.f};

    auto stage = [&](int kb, int buf) {
        _Float16* dA = lds + buf * 16384;
        _Float16* dB = dA + 8192;
        #pragma unroll
        for (int jj = 0; jj < 4; ++jj) {   // A: 8 x 128B contiguous runs / instr
            int j = w + jj * 4;
            gl_lds16(A + (size_t)tokR[jj] * AS + kb * 64 + cSt * 8, (void*)(dA + j * 512));
        }
        const _Float16* wb = wtile + (size_t)kb * 8192;
        #pragma unroll
        for (int jj = 0; jj < 4; ++jj) {   // B: contiguous 1KB / instr
            int j = w + jj * 4;
            gl_lds16(wb + j * 512 + lane * 8, (void*)(dB + j * 512));
        }
    };

    auto compute = [&](int buf) {
        const _Float16* bA = lds + buf * 16384;
        const _Float16* bB = bA + 8192;
        if constexpr (SPLIT) {
            half8 ah[4], al[4];
            #pragma unroll
            for (int mi = 0; mi < 4; ++mi) {
                int r = r0 + mi * 16 + l15;
                int ph = q ^ (r & 7), pl = (q + 4) ^ (r & 7);
                ah[mi] = *(const half8*)(bA + r * 64 + ph * 8);
                al[mi] = *(const half8*)(bA + r * 64 + pl * 8);
            }
            #pragma unroll
            for (int ni = 0; ni < 4; ++ni) {
                int r = c0 + ni * 16 + l15;
                int ph = q ^ (r & 7), pl = (q + 4) ^ (r & 7);
                half8 bh = *(const half8*)(bB + r * 64 + ph * 8);
                half8 bl = *(const half8*)(bB + r * 64 + pl * 8);
                #pragma unroll
                for (int mi = 0; mi < 4; ++mi) accu[mi][ni] = MFMA_F16(ah[mi], bh, accu[mi][ni]);
                #pragma unroll
                for (int mi = 0; mi < 4; ++mi) accu[mi][ni] = MFMA_F16(ah[mi], bl, accu[mi][ni]);
                #pragma unroll
                for (int mi = 0; mi < 4; ++mi) accu[mi][ni] = MFMA_F16(al[mi], bh, accu[mi][ni]);
            }
        } else {
            #pragma unroll
            for (int ks = 0; ks < 2; ++ks) {
                half8 a[4];
                #pragma unroll
                for (int mi = 0; mi < 4; ++mi) {
                    int r = r0 + mi * 16 + l15;
                    int pc = (ks * 4 + q) ^ (r & 7);
                    a[mi] = *(const half8*)(bA + r * 64 + pc * 8);
                }
                #pragma unroll
                for (int ni = 0; ni < 4; ++ni) {
                    int r = c0 + ni * 16 + l15;
                    int pc = (ks * 4 + q) ^ (r & 7);
                    half8 b = *(const half8*)(bB + r * 64 + pc * 8);
                    #pragma unroll
                    for (int mi = 0; mi < 4; ++mi) accu[mi][ni] = MFMA_F16(a[mi], b, accu[mi][ni]);
                }
            }
        }
    };

    stage(0, 0);
    __syncthreads();
    int cur = 0;
    for (int kb = 0; kb < KIT - 1; ++kb) {
        stage(kb + 1, cur ^ 1);      // issue next tile's loads FIRST
        compute(cur);                // ds_read + MFMA current tile
        __syncthreads();             // single drain per K-step
        cur ^= 1;
    }
    compute(cur);

    // epilogue: C/D layout col=lane&15, row=(lane>>4)*4+reg
    float tsc = *tscp, iae = iav[e];
    float bv[4];
    #pragma unroll
    for (int ni = 0; ni < 4; ++ni) bv[ni] = bias[e * DM + n0 + c0 + ni * 16 + l15];
    #pragma unroll
    for (int mi = 0; mi < 4; ++mi) {
        int liBase = r0 + mi * 16 + q * 4;
        #pragma unroll
        for (int reg = 0; reg < 4; ++reg) {
            int li = liBase + reg;
            if (li < valid) {
                int tok = tokLds[li];
                float2 wp = wts[tok];
                float wgt = slot ? wp.y : wp.x;
                float sg = tsc * wgt * iae, sb = tsc * wgt;
                float* orow = outp + (size_t)tok * DM + n0;
                #pragma unroll
                for (int ni = 0; ni < 4; ++ni) {
                    float v = accu[mi][ni][reg] * sg + bv[ni] * sb;
                    int c = c0 + ni * 16 + l15;
                    if (accum) orow[c] += v; else orow[c] = v;
                }
            }
        }
    }
}

// =============================== finalize aux ===============================
__global__ void finalize_kernel(const float* __restrict__ ctrl, float* __restrict__ outp)
{
    if (threadIdx.x == 0) {
        float aux = 0.f;
        for (int l = 0; l < 2; ++l) {
            float vq = ctrl[48 + l] / (float)NTOK;
            float mean = 0.f;
            for (int e = 0; e < 8; ++e) mean += ctrl[32 + l * 8 + e];
            mean *= 0.125f;
            float s = 0.f;
            for (int e = 0; e < 8; ++e) {
                float d = ctrl[32 + l * 8 + e] - mean;
                s += d * d;
            }
            float var = s / 7.f;                       // ddof=1
            float lb = var / (mean * mean + 1e-10f);
            aux += 0.05f * vq + 0.01f * lb;
        }
        *outp = aux;
    }
}

// =============================== launch ===============================
extern "C" void kernel_launch(void* const* d_in, const int* in_sizes, int n_in,
                              void* d_out, int out_size, void* d_ws, size_t ws_size,
                              hipStream_t stream) {
    const float* x     = (const float*)d_in[0];
    const float* rm0   = (const float*)d_in[1];
    const float* W0    = (const float*)d_in[2];
    const float* b0    = (const float*)d_in[3];
    const float* temp0 = (const float*)d_in[4];
    const float* ca0   = (const float*)d_in[5];
    const float* rm1   = (const float*)d_in[6];
    const float* W1    = (const float*)d_in[7];
    const float* b1    = (const float*)d_in[8];
    const float* temp1 = (const float*)d_in[9];
    const float* ca1   = (const float*)d_in[10];
    float* out = (float*)d_out;

    char* ws = (char*)d_ws;
    float* ctrl = (float*)ws;
    int*   cnt  = (int*)ctrl;                 // [2][2][8]
    float* imp  = ctrl + 32;                  // [2][8]
    float* vq   = ctrl + 48;                  // [2]
    float* tsc  = ctrl + 50;                  // [2]
    float* ia   = ctrl + 52;                  // [2][8]
    float* rmn  = ctrl + 128;                 // [16][512]
    float2*        wts = (float2*)(ws + (size_t)64  * 1024);  // [2][16384]
    float2*        bs  = (float2*)(ws + (size_t)384 * 1024);  // [2][16384]
    unsigned char* key = (unsigned char*)(ws + (size_t)704 * 1024); // [2][2][16384]

    char* big = ws + (1 << 20);
    half8*          w0pk8 = (half8*)(big);                                 // 8MB
    half8*          w1pk8 = (half8*)(big + (size_t)8  * 1024 * 1024);      // 4MB
    const _Float16* w0pk  = (const _Float16*)w0pk8;
    const _Float16* w1pk  = (const _Float16*)w1pk8;
    _Float16*       h16   = (_Float16*)(big + (size_t)12 * 1024 * 1024);   // 16MB
    unsigned short* bkt   = (unsigned short*)(big + (size_t)28 * 1024 * 1024); // 2MB
    // total ws use: 31MB

    // xpk (interleaved hi/lo activations) lives in d_out's h1 region (32MB),
    // dead until layer-1 GEMMs write h1.
    _Float16* xpk = (_Float16*)(out + (size_t)NTOK * DM);

    prep_kernel<<<1, 256, 0, stream>>>(rm0, rm1, ca0, ca1, temp0, temp1, ctrl, rmn);
    pack_w_kernel<<<3072, 256, 0, stream>>>(W0, W1, w0pk8, w1pk8);

    // layer 0
    route_kernel<<<4096, 256, 0, stream>>>(x, rmn, 0, 1, xpk, key, wts, bs);
    compact_kernel<<<dim3(16, 8), 256, 0, stream>>>(key, wts, bs, cnt, bkt, imp, vq);
    gemm_kernel<true><<<dim3(135, 4), 256, 0, stream>>>(xpk, w0pk, b0, ia, tsc,
        cnt, bkt, wts, 0, 0, out);
    gemm_kernel<true><<<dim3(135, 4), 256, 0, stream>>>(xpk, w0pk, b0, ia, tsc,
        cnt + 8, bkt + 8 * NTOK, wts, 1, 1, out);

    // layer 1 (routes on h_emb in d_out; relu + h->fp16 fused in route)
    route_kernel<<<4096, 256, 0, stream>>>(out, rmn + 4096, 1, 0, h16,
        key + 2 * NTOK, wts + NTOK, bs + NTOK);
    compact_kernel<<<dim3(16, 8), 256, 0, stream>>>(key + 2 * NTOK, wts + NTOK, bs + NTOK,
        cnt + 16, bkt + 16 * NTOK, imp + 8, vq + 1);
    gemm_kernel<false><<<dim3(135, 4), 256, 0, stream>>>(h16, w1pk, b1, ia + 8, tsc + 1,
        cnt + 16, bkt + 16 * NTOK, wts + NTOK, 0, 0, out + (size_t)NTOK * DM);
    gemm_kernel<false><<<dim3(135, 4), 256, 0, stream>>>(h16, w1pk, b1, ia + 8, tsc + 1,
        cnt + 24, bkt + 24 * NTOK, wts + NTOK, 1, 1, out + (size_t)NTOK * DM);

    finalize_kernel<<<1, 64, 0, stream>>>(ctrl, out + (size_t)2 * NTOK * DM);
}

// Round 3
// 464.929 us; speedup vs baseline: 1.1414x; 1.0464x over previous
//
#include <hip/hip_runtime.h>
#include <cmath>
#include <cstdint>

#define NTOK   16384
#define NEXP   8
#define DM     512
#define LOG100 4.605170185988092f

typedef _Float16 half8  __attribute__((ext_vector_type(8)));
typedef float    floatx4 __attribute__((ext_vector_type(4)));

#define MFMA_F16(a, b, c) __builtin_amdgcn_mfma_f32_16x16x32_f16((a), (b), (c), 0, 0, 0)

// async global->LDS, 16B per lane. LDS dest wave-uniform base (HW adds lane*16);
// global source address is per-lane.
__device__ __forceinline__ void gl_lds16(const void* g, void* l) {
    __builtin_amdgcn_global_load_lds(
        (const __attribute__((address_space(1))) void*)g,
        (__attribute__((address_space(3))) void*)l, 16, 0, 0);
}

// ---------------- ws layout ----------------
// ctrl floats @ws: [0..31] int cnt[2][2][8] | [32..47] imp[2][8] | [48..49] vq[2]
//                  [50..51] tsc[2] | [52..67] ia[2][8] | [128..8319] rmn[16*512]
// @ws+64KB:  float2 wts[2][16384]  (256KB)
// @ws+384KB: float2 bs[2][16384]   (256KB)
// @ws+704KB: uchar key[2][2][16384] (64KB)
// @ws+1MB:   w0pk 8MB | w1pk 4MB | h16 16MB | bkt(ushort) 2MB  => 31MB total
// xpk (32MB, interleaved hi/lo) lives in d_out's h1 region (dead until layer-1 GEMMs).

// =============================== prep ===============================
__global__ __launch_bounds__(256) void prep_kernel(
    const float* __restrict__ rm0, const float* __restrict__ rm1,
    const float* __restrict__ ca0, const float* __restrict__ ca1,
    const float* __restrict__ temp0, const float* __restrict__ temp1,
    float* __restrict__ ctrl, float* __restrict__ rmn)
{
    int tid = threadIdx.x, lane = tid & 63, w = tid >> 6;
    if (tid < 32) ((int*)ctrl)[tid] = 0;                       // cnt
    if (tid >= 32 && tid < 48) ctrl[tid] = 0.f;                // imp
    if (tid == 48 || tid == 49) ctrl[tid] = 0.f;               // vq
    if (tid == 50) ctrl[50] = expf(fminf(temp0[0], LOG100));
    if (tid == 51) ctrl[51] = expf(fminf(temp1[0], LOG100));
    if (tid >= 52 && tid < 68) {
        int i = tid - 52;
        ctrl[tid] = expf(fminf(i < 8 ? ca0[i] : ca1[i - 8], LOG100));
    }
    for (int r = w; r < 16; r += 4) {
        const float* src = (r < 8) ? (rm0 + r * DM) : (rm1 + (r - 8) * DM);
        float v[8]; float ss = 0.f;
        #pragma unroll
        for (int j = 0; j < 8; ++j) { v[j] = src[lane + 64 * j]; ss += v[j] * v[j]; }
        #pragma unroll
        for (int off = 32; off > 0; off >>= 1) ss += __shfl_xor(ss, off);
        float inv = 1.f / fmaxf(sqrtf(ss), 1e-12f);
        float* dst = rmn + r * DM;
        #pragma unroll
        for (int j = 0; j < 8; ++j) dst[lane + 64 * j] = v[j] * inv;
    }
}

// =============================== W tile pre-pack ===============================
// Packs W into the EXACT swizzled LDS image the GEMM stages, so every
// global_load_lds is a contiguous 1KB copy.
// w0pk: [e][nt(4)][kb(16)][j(16)][lane(64)][8 halves]; lane=(s,p): row=j*8+s,
//       chunk c=p^s: c<4 -> fp16-hi of W0[e][n][kb*32+c*8 ..+7], c>=4 -> fp16-lo.
// w1pk: [e][nt(4)][kb(8)][j(16)][lane][8]: chunk c=p^s -> W1[e][n][kb*64+c*8 ..].
__global__ __launch_bounds__(256) void pack_w_kernel(
    const float* __restrict__ W0, const float* __restrict__ W1,
    half8* __restrict__ w0pk, half8* __restrict__ w1pk)
{
    int i = blockIdx.x * 256 + threadIdx.x;      // 3072*256 = 768K = 512K(W0)+256K(W1)
    if (i < 512 * 1024) {
        int l = i & 63, j = (i >> 6) & 15, kb = (i >> 10) & 15, nt = (i >> 14) & 3, e = i >> 16;
        int s = l >> 3, p = l & 7, c = p ^ s;
        int n = nt * 128 + j * 8 + s;
        int k = kb * 32 + (c & 3) * 8;
        const float* src = W0 + ((size_t)e * DM + n) * DM + k;
        half8 v;
        #pragma unroll
        for (int t = 0; t < 8; ++t) {
            float f = src[t];
            _Float16 h = (_Float16)f;
            v[t] = (c < 4) ? h : (_Float16)(f - (float)h);
        }
        w0pk[i] = v;
    } else {
        int m = i - 512 * 1024;
        int l = m & 63, j = (m >> 6) & 15, kb = (m >> 10) & 7, nt = (m >> 13) & 3, e = m >> 15;
        int s = l >> 3, p = l & 7, c = p ^ s;
        int n = nt * 128 + j * 8 + s;
        int k = kb * 64 + c * 8;
        const float* src = W1 + ((size_t)e * DM + n) * DM + k;
        half8 v;
        #pragma unroll
        for (int t = 0; t < 8; ++t) v[t] = (_Float16)src[t];
        w1pk[m] = v;
    }
}

// =============================== routing (1 token / wave) ===============================
// split=1: writes interleaved hi/lo activation rows: xpk[tok][kb(16)][32 hi | 32 lo]
//          => each (tok,kb) is one contiguous 128B run for the GEMM's A staging.
// split=0: plain fp16 row [tok][512] (layer-1; already 128B-contiguous per (tok,kb)).
__global__ __launch_bounds__(256) void route_kernel(
    const float* __restrict__ src,      // [16384][512]
    const float* __restrict__ rmn,      // [8*512] normalized memory (this layer)
    int relu_in, int split,
    _Float16* __restrict__ dst,
    unsigned char* __restrict__ key,    // [2][16384] this layer (slot-major)
    float2* __restrict__ wts,           // [16384]
    float2* __restrict__ bs)            // [16384] (best,second)
{
    __shared__ float rmLds[NEXP * DM];
    int tid = threadIdx.x;
    for (int i = tid; i < NEXP * DM; i += 256) rmLds[i] = rmn[i];
    __syncthreads();
    int lane = tid & 63, w = tid >> 6;
    int token = blockIdx.x * 4 + w;

    const float* row = src + (size_t)token * DM;
    float x[8]; float ss = 0.f;
    #pragma unroll
    for (int j = 0; j < 8; ++j) {
        float v = row[lane + 64 * j];
        if (relu_in) v = fmaxf(v, 0.f);
        x[j] = v; ss += v * v;
    }
    if (split) {
        #pragma unroll
        for (int j = 0; j < 8; ++j) {
            int k = lane + 64 * j;
            size_t base = (size_t)token * 1024 + (size_t)((k >> 5) << 6) + (k & 31);
            _Float16 h = (_Float16)x[j];
            dst[base] = h;
            dst[base + 32] = (_Float16)(x[j] - (float)h);
        }
    } else {
        #pragma unroll
        for (int j = 0; j < 8; ++j)
            dst[(size_t)token * DM + lane + 64 * j] = (_Float16)x[j];
    }
    float d[8];
    #pragma unroll
    for (int e = 0; e < 8; ++e) {
        float a = 0.f;
        #pragma unroll
        for (int j = 0; j < 8; ++j) a += x[j] * rmLds[e * DM + lane + 64 * j];
        d[e] = a;
    }
    #pragma unroll
    for (int off = 32; off > 0; off >>= 1) {
        ss += __shfl_xor(ss, off);
        #pragma unroll
        for (int e = 0; e < 8; ++e) d[e] += __shfl_xor(d[e], off);
    }
    float inv = 1.f / fmaxf(sqrtf(ss), 1e-12f);
    float best = -1e30f, second = -1e30f; int be = 0, se = 0;
    #pragma unroll
    for (int e = 0; e < 8; ++e) {
        float de = d[e] * inv;
        if (de > best)        { second = best; se = be; best = de; be = e; }
        else if (de > second) { second = de; se = e; }
    }
    float z = expf(second - best);
    float w0 = 1.f / (1.f + z), w1 = z / (1.f + z);
    if (lane == 0) {
        key[token] = (unsigned char)be;
        key[NTOK + token] = (unsigned char)se;
        wts[token] = make_float2(w0, w1);
        bs[token] = make_float2(best, second);
    }
}

// =============================== bucket compaction ===============================
// grid (16, 8): blockIdx.x = slot*8+e, blockIdx.y = 2048-token chunk.
// Wave-level compaction with atomic base allocation (no barriers in the scan).
// Bucket order is arbitrary -- numerically irrelevant.
__global__ __launch_bounds__(256) void compact_kernel(
    const unsigned char* __restrict__ key,  // [2][16384] this layer
    const float2* __restrict__ wts,         // [16384]
    const float2* __restrict__ bs,          // [16384]
    int* __restrict__ cnt,                  // [2][8] this layer (pre-zeroed by prep)
    unsigned short* __restrict__ bkt,       // [2][8][16384] this layer
    float* __restrict__ imp,                // [8] this layer
    float* __restrict__ vq_acc)             // &vq[layer]
{
    int slot = blockIdx.x >> 3, e = blockIdx.x & 7;
    int chunk = blockIdx.y;
    const unsigned char* k = key + slot * NTOK;
    unsigned short* ob = bkt + (size_t)(slot * 8 + e) * NTOK;
    int tid = threadIdx.x, lane = tid & 63, w = tid >> 6;
    float wsum = 0.f, vqs = 0.f;
    for (int c = 0; c < 8; ++c) {
        int tok = chunk * 2048 + c * 256 + tid;
        bool m = (k[tok] == (unsigned char)e);
        unsigned long long mask = __ballot(m);
        int wcount = __popcll(mask);
        int wbase = 0;
        if (lane == 0 && wcount) wbase = atomicAdd(&cnt[slot * 8 + e], wcount);
        wbase = __shfl(wbase, 0);
        if (m) {
            int pre = __popcll(mask & ((1ull << lane) - 1ull));
            ob[wbase + pre] = (unsigned short)tok;
            float2 wp = wts[tok]; float2 b2 = bs[tok];
            float wv = slot ? wp.y : wp.x;
            wsum += wv;
            vqs  += wv * (slot ? b2.y : b2.x);
        }
    }
    #pragma unroll
    for (int off = 32; off > 0; off >>= 1) {
        wsum += __shfl_xor(wsum, off);
        vqs  += __shfl_xor(vqs, off);
    }
    __shared__ float rw[4], rv[4];
    if (lane == 0) { rw[w] = wsum; rv[w] = vqs; }
    __syncthreads();
    if (tid == 0) {
        atomicAdd(&imp[e], rw[0] + rw[1] + rw[2] + rw[3]);
        atomicAdd(vq_acc, -(rv[0] + rv[1] + rv[2] + rv[3]));
    }
}

// =============================== grouped GEMM ===============================
// 1D grid 544 = 8 XCDs x 68 slots; assumed dispatch mapping xcd = blockIdx.x % 8.
// XCD c owns m-tiles [17c, 17c+17); slot s in [0,68): tile = 17c + (s>>2), nt = s&3.
// -> an m-tile's 4 n-tiles run back-to-back on ONE XCD: its A panel (256KB) is
//    fetched once and L2-hit 3x; each expert's packed-B image also stays on ~1 XCD.
// Tile (e, m0) decoded from a prefix sum over cnt[8] (<=135 tiles < 136 slots).
//
// 128x128 tile, 4 waves (2x2 of 64x64), 16x16x32 f16 MFMA.
// T4 counted-vmcnt pipeline: raw s_barrier + s_waitcnt vmcnt(8) -- the 8 loads of
// tile kb+1 stay IN FLIGHT across both barriers; a stage issued at the end of
// iter kb is awaited at the start of iter kb+2 (one full iteration of latency
// hiding). No vmcnt(0) drain in the main loop.
// Safety: every ds_read is lgkmcnt-retired before its consuming MFMA issues
// (compiler-inserted), hence before barrier #2; stage(kb+2) is issued only after
// barrier #2; vmcnt(8)+barrier #1 publishes each wave's staged quarter.
// SPLIT: KSTEP=32, chunks 0-3=hi 4-7=lo, 3 MFMA passes. Plain: KSTEP=64.
template <bool SPLIT>
__global__ __launch_bounds__(256) void gemm_kernel(
    const _Float16* __restrict__ A,      // SPLIT: xpk [tok][1024] ; else h16 [tok][512]
    const _Float16* __restrict__ Wpk,    // packed tiles
    const float* __restrict__ bias,      // [8][512]
    const float* __restrict__ iav,       // [8]
    const float* __restrict__ tscp,
    const int* __restrict__ cnt,         // [8] this layer+slot
    const unsigned short* __restrict__ bkt, // [8][16384]
    const float2* __restrict__ wts,      // [16384]
    int slot, int accum,
    float* __restrict__ outp)
{
    __shared__ __align__(16) _Float16 lds[2 * 16384];
    __shared__ int tokLds[128];

    int p = blockIdx.x;
    int xcd = p & 7, s = p >> 3;
    int t = xcd * 17 + (s >> 2), nt = s & 3;
    int e = -1, m0 = 0, M = 0, acc = 0;
    #pragma unroll
    for (int ee = 0; ee < 8; ++ee) {
        int Me = cnt[ee];
        int ne = (Me + 127) >> 7;
        if (t >= acc && t < acc + ne) { e = ee; m0 = (t - acc) << 7; M = Me; }
        acc += ne;
    }
    if (e < 0) return;                   // t beyond total tiles (<= 8 blocks)
    int n0 = nt << 7;
    int valid = min(128, M - m0);
    int tid = threadIdx.x, lane = tid & 63, w = tid >> 6;
    if (tid < 128) tokLds[tid] = bkt[e * NTOK + m0 + min(tid, valid - 1)];
    __syncthreads();

    int subRow = lane >> 3, pp = lane & 7;
    int cSt = pp ^ subRow;
    int wm = w >> 1, wn = w & 1;
    int r0 = wm * 64, c0 = wn * 64;
    int q = lane >> 4, l15 = lane & 15;

    constexpr int KIT = SPLIT ? 16 : 8;
    constexpr int AS  = SPLIT ? 1024 : 512;

    int tokR[4];
    #pragma unroll
    for (int jj = 0; jj < 4; ++jj) tokR[jj] = tokLds[(w + jj * 4) * 8 + subRow];

    const _Float16* wtile = Wpk + (size_t)(e * 4 + nt) * KIT * 8192;

    floatx4 accu[4][4];
    #pragma unroll
    for (int mi = 0; mi < 4; ++mi)
        #pragma unroll
        for (int ni = 0; ni < 4; ++ni) accu[mi][ni] = (floatx4){0.f, 0.f, 0.f, 0.f};

    auto stage = [&](int kb, int buf) {
        _Float16* dA = lds + buf * 16384;
        _Float16* dB = dA + 8192;
        #pragma unroll
        for (int jj = 0; jj < 4; ++jj) {   // A: 8 x 128B contiguous runs / instr
            int j = w + jj * 4;
            gl_lds16(A + (size_t)tokR[jj] * AS + kb * 64 + cSt * 8, (void*)(dA + j * 512));
        }
        const _Float16* wb = wtile + (size_t)kb * 8192;
        #pragma unroll
        for (int jj = 0; jj < 4; ++jj) {   // B: contiguous 1KB / instr
            int j = w + jj * 4;
            gl_lds16(wb + j * 512 + lane * 8, (void*)(dB + j * 512));
        }
    };

    auto compute = [&](int buf) {
        const _Float16* bA = lds + buf * 16384;
        const _Float16* bB = bA + 8192;
        if constexpr (SPLIT) {
            half8 ah[4], al[4];
            #pragma unroll
            for (int mi = 0; mi < 4; ++mi) {
                int r = r0 + mi * 16 + l15;
                int ph = q ^ (r & 7), pl = (q + 4) ^ (r & 7);
                ah[mi] = *(const half8*)(bA + r * 64 + ph * 8);
                al[mi] = *(const half8*)(bA + r * 64 + pl * 8);
            }
            #pragma unroll
            for (int ni = 0; ni < 4; ++ni) {
                int r = c0 + ni * 16 + l15;
                int ph = q ^ (r & 7), pl = (q + 4) ^ (r & 7);
                half8 bh = *(const half8*)(bB + r * 64 + ph * 8);
                half8 bl = *(const half8*)(bB + r * 64 + pl * 8);
                #pragma unroll
                for (int mi = 0; mi < 4; ++mi) accu[mi][ni] = MFMA_F16(ah[mi], bh, accu[mi][ni]);
                #pragma unroll
                for (int mi = 0; mi < 4; ++mi) accu[mi][ni] = MFMA_F16(ah[mi], bl, accu[mi][ni]);
                #pragma unroll
                for (int mi = 0; mi < 4; ++mi) accu[mi][ni] = MFMA_F16(al[mi], bh, accu[mi][ni]);
            }
        } else {
            #pragma unroll
            for (int ks = 0; ks < 2; ++ks) {
                half8 a[4];
                #pragma unroll
                for (int mi = 0; mi < 4; ++mi) {
                    int r = r0 + mi * 16 + l15;
                    int pc = (ks * 4 + q) ^ (r & 7);
                    a[mi] = *(const half8*)(bA + r * 64 + pc * 8);
                }
                #pragma unroll
                for (int ni = 0; ni < 4; ++ni) {
                    int r = c0 + ni * 16 + l15;
                    int pc = (ks * 4 + q) ^ (r & 7);
                    half8 b = *(const half8*)(bB + r * 64 + pc * 8);
                    #pragma unroll
                    for (int mi = 0; mi < 4; ++mi) accu[mi][ni] = MFMA_F16(a[mi], b, accu[mi][ni]);
                }
            }
        }
    };

    // ---- T4 pipeline: loads for tile kb+1 stay in flight across barriers ----
    stage(0, 0);
    stage(1, 1);
    for (int kb = 0; kb < KIT - 1; ++kb) {
        asm volatile("s_waitcnt vmcnt(8)" ::: "memory");  // tile kb landed (newest 8 = kb+1 still flying)
        __builtin_amdgcn_s_barrier();
        __builtin_amdgcn_sched_barrier(0);
        compute(kb & 1);
        __builtin_amdgcn_sched_barrier(0);
        __builtin_amdgcn_s_barrier();                     // all waves done READING buf[kb&1]
        if (kb + 2 < KIT) stage(kb + 2, kb & 1);
    }
    asm volatile("s_waitcnt vmcnt(0)" ::: "memory");
    __builtin_amdgcn_s_barrier();
    __builtin_amdgcn_sched_barrier(0);
    compute((KIT - 1) & 1);

    // epilogue: C/D layout col=lane&15, row=(lane>>4)*4+reg
    float tsc = *tscp, iae = iav[e];
    float bv[4];
    #pragma unroll
    for (int ni = 0; ni < 4; ++ni) bv[ni] = bias[e * DM + n0 + c0 + ni * 16 + l15];
    #pragma unroll
    for (int mi = 0; mi < 4; ++mi) {
        int liBase = r0 + mi * 16 + q * 4;
        #pragma unroll
        for (int reg = 0; reg < 4; ++reg) {
            int li = liBase + reg;
            if (li < valid) {
                int tok = tokLds[li];
                float2 wp = wts[tok];
                float wgt = slot ? wp.y : wp.x;
                float sg = tsc * wgt * iae, sb = tsc * wgt;
                float* orow = outp + (size_t)tok * DM + n0;
                #pragma unroll
                for (int ni = 0; ni < 4; ++ni) {
                    float v = accu[mi][ni][reg] * sg + bv[ni] * sb;
                    int c = c0 + ni * 16 + l15;
                    if (accum) orow[c] += v; else orow[c] = v;
                }
            }
        }
    }
}

// =============================== finalize aux ===============================
__global__ void finalize_kernel(const float* __restrict__ ctrl, float* __restrict__ outp)
{
    if (threadIdx.x == 0) {
        float aux = 0.f;
        for (int l = 0; l < 2; ++l) {
            float vq = ctrl[48 + l] / (float)NTOK;
            float mean = 0.f;
            for (int e = 0; e < 8; ++e) mean += ctrl[32 + l * 8 + e];
            mean *= 0.125f;
            float s = 0.f;
            for (int e = 0; e < 8; ++e) {
                float d = ctrl[32 + l * 8 + e] - mean;
                s += d * d;
            }
            float var = s / 7.f;                       // ddof=1
            float lb = var / (mean * mean + 1e-10f);
            aux += 0.05f * vq + 0.01f * lb;
        }
        *outp = aux;
    }
}

// =============================== launch ===============================
extern "C" void kernel_launch(void* const* d_in, const int* in_sizes, int n_in,
                              void* d_out, int out_size, void* d_ws, size_t ws_size,
                              hipStream_t stream) {
    const float* x     = (const float*)d_in[0];
    const float* rm0   = (const float*)d_in[1];
    const float* W0    = (const float*)d_in[2];
    const float* b0    = (const float*)d_in[3];
    const float* temp0 = (const float*)d_in[4];
    const float* ca0   = (const float*)d_in[5];
    const float* rm1   = (const float*)d_in[6];
    const float* W1    = (const float*)d_in[7];
    const float* b1    = (const float*)d_in[8];
    const float* temp1 = (const float*)d_in[9];
    const float* ca1   = (const float*)d_in[10];
    float* out = (float*)d_out;

    char* ws = (char*)d_ws;
    float* ctrl = (float*)ws;
    int*   cnt  = (int*)ctrl;                 // [2][2][8]
    float* imp  = ctrl + 32;                  // [2][8]
    float* vq   = ctrl + 48;                  // [2]
    float* tsc  = ctrl + 50;                  // [2]
    float* ia   = ctrl + 52;                  // [2][8]
    float* rmn  = ctrl + 128;                 // [16][512]
    float2*        wts = (float2*)(ws + (size_t)64  * 1024);  // [2][16384]
    float2*        bs  = (float2*)(ws + (size_t)384 * 1024);  // [2][16384]
    unsigned char* key = (unsigned char*)(ws + (size_t)704 * 1024); // [2][2][16384]

    char* big = ws + (1 << 20);
    half8*          w0pk8 = (half8*)(big);                                 // 8MB
    half8*          w1pk8 = (half8*)(big + (size_t)8  * 1024 * 1024);      // 4MB
    const _Float16* w0pk  = (const _Float16*)w0pk8;
    const _Float16* w1pk  = (const _Float16*)w1pk8;
    _Float16*       h16   = (_Float16*)(big + (size_t)12 * 1024 * 1024);   // 16MB
    unsigned short* bkt   = (unsigned short*)(big + (size_t)28 * 1024 * 1024); // 2MB
    // total ws use: 31MB

    // xpk (interleaved hi/lo activations) lives in d_out's h1 region (32MB),
    // dead until layer-1 GEMMs write h1.
    _Float16* xpk = (_Float16*)(out + (size_t)NTOK * DM);

    prep_kernel<<<1, 256, 0, stream>>>(rm0, rm1, ca0, ca1, temp0, temp1, ctrl, rmn);
    pack_w_kernel<<<3072, 256, 0, stream>>>(W0, W1, w0pk8, w1pk8);

    // layer 0
    route_kernel<<<4096, 256, 0, stream>>>(x, rmn, 0, 1, xpk, key, wts, bs);
    compact_kernel<<<dim3(16, 8), 256, 0, stream>>>(key, wts, bs, cnt, bkt, imp, vq);
    gemm_kernel<true><<<544, 256, 0, stream>>>(xpk, w0pk, b0, ia, tsc,
        cnt, bkt, wts, 0, 0, out);
    gemm_kernel<true><<<544, 256, 0, stream>>>(xpk, w0pk, b0, ia, tsc,
        cnt + 8, bkt + 8 * NTOK, wts, 1, 1, out);

    // layer 1 (routes on h_emb in d_out; relu + h->fp16 fused in route)
    route_kernel<<<4096, 256, 0, stream>>>(out, rmn + 4096, 1, 0, h16,
        key + 2 * NTOK, wts + NTOK, bs + NTOK);
    compact_kernel<<<dim3(16, 8), 256, 0, stream>>>(key + 2 * NTOK, wts + NTOK, bs + NTOK,
        cnt + 16, bkt + 16 * NTOK, imp + 8, vq + 1);
    gemm_kernel<false><<<544, 256, 0, stream>>>(h16, w1pk, b1, ia + 8, tsc + 1,
        cnt + 16, bkt + 16 * NTOK, wts + NTOK, 0, 0, out + (size_t)NTOK * DM);
    gemm_kernel<false><<<544, 256, 0, stream>>>(h16, w1pk, b1, ia + 8, tsc + 1,
        cnt + 24, bkt + 24 * NTOK, wts + NTOK, 1, 1, out + (size_t)NTOK * DM);

    finalize_kernel<<<1, 64, 0, stream>>>(ctrl, out + (size_t)2 * NTOK * DM);
}